// Round 2
// baseline (429.588 us; speedup 1.0000x reference)
//
#include <hip/hip_runtime.h>

#define H 1024
#define B 64
#define L 1024

// ---------------------------------------------------------------------------
// Kernel A: v[b,h] = sum_g hidden[b,g] * W[g,h]   (v = hidden @ W, 64x1024)
// grid: B * (H/256) = 256 blocks, 256 threads. Hidden row staged in LDS.
// W reads are coalesced (lane i -> W[g*H + h0 + i]).
// ---------------------------------------------------------------------------
__global__ __launch_bounds__(256) void proj_hidden_kernel(
    const float* __restrict__ hidden,
    const float* __restrict__ W,
    float* __restrict__ v) {
    __shared__ float sh[H];
    const int bid   = blockIdx.x;
    const int b     = bid >> 2;   // / (H/256)
    const int chunk = bid & 3;
    const int tid   = threadIdx.x;

    for (int i = tid; i < H; i += 256) sh[i] = hidden[b * H + i];
    __syncthreads();

    const int h = chunk * 256 + tid;
    float acc = 0.f;
#pragma unroll 8
    for (int g = 0; g < H; ++g) {
        acc += sh[g] * W[(size_t)g * H + h];
    }
    v[b * H + h] = acc;
}

// ---------------------------------------------------------------------------
// Kernel B: e[b,l] = dot(v[b,:], enc[l,b,:])
// One 64-lane wave per (l,b) pair; float4 loads (16B/lane), shfl reduction.
// enc[l,b,:] is 4KB contiguous; 4 consecutive waves in a block read a
// contiguous 16KB span (b varies fastest).
// ---------------------------------------------------------------------------
__global__ __launch_bounds__(256) void energy_kernel(
    const float* __restrict__ enc,
    const float* __restrict__ v,
    float* __restrict__ e) {
    const int wave = (blockIdx.x * 256 + threadIdx.x) >> 6;
    const int lane = threadIdx.x & 63;
    const int b = wave & (B - 1);
    const int l = wave >> 6;   // wave / B

    const float4* __restrict__ ep =
        reinterpret_cast<const float4*>(enc + ((size_t)l * B + b) * H);
    const float4* __restrict__ vp =
        reinterpret_cast<const float4*>(v + (size_t)b * H);

    float acc = 0.f;
#pragma unroll
    for (int k = 0; k < 4; ++k) {
        float4 a = ep[lane + k * 64];
        float4 w = vp[lane + k * 64];
        acc += a.x * w.x + a.y * w.y + a.z * w.z + a.w * w.w;
    }
#pragma unroll
    for (int off = 32; off; off >>= 1) acc += __shfl_down(acc, off, 64);
    if (lane == 0) e[(size_t)b * L + l] = acc;
}

// ---------------------------------------------------------------------------
// Kernel C: row softmax over L=1024 per batch. 64 blocks x 1024 threads.
// (Bias term c[b] omitted: softmax is invariant to a per-row constant.)
// ---------------------------------------------------------------------------
__global__ __launch_bounds__(1024) void softmax_kernel(
    const float* __restrict__ e,
    float* __restrict__ out) {
    const int b = blockIdx.x;
    const int tid = threadIdx.x;
    const int wid = tid >> 6, lane = tid & 63;
    __shared__ float red[16];

    float x = e[(size_t)b * L + tid];

    // --- row max ---
    float m = x;
#pragma unroll
    for (int off = 32; off; off >>= 1) m = fmaxf(m, __shfl_down(m, off, 64));
    if (lane == 0) red[wid] = m;
    __syncthreads();
    if (tid < 16) {
        float t = red[tid];
#pragma unroll
        for (int off = 8; off; off >>= 1) t = fmaxf(t, __shfl_down(t, off, 16));
        if (tid == 0) red[0] = t;
    }
    __syncthreads();
    m = red[0];
    __syncthreads();

    // --- exp + row sum ---
    float ex = __expf(x - m);
    float s = ex;
#pragma unroll
    for (int off = 32; off; off >>= 1) s += __shfl_down(s, off, 64);
    if (lane == 0) red[wid] = s;
    __syncthreads();
    if (tid < 16) {
        float t = red[tid];
#pragma unroll
        for (int off = 8; off; off >>= 1) t += __shfl_down(t, off, 16);
        if (tid == 0) red[0] = t;
    }
    __syncthreads();
    s = red[0];

    out[(size_t)b * L + tid] = ex / s;
}

extern "C" void kernel_launch(void* const* d_in, const int* in_sizes, int n_in,
                              void* d_out, int out_size, void* d_ws, size_t ws_size,
                              hipStream_t stream) {
    const float* hidden = (const float*)d_in[0];   // (1, B, H)
    const float* enc    = (const float*)d_in[1];   // (L, B, H)
    const float* W      = (const float*)d_in[2];   // (H, H)
    // d_in[3] = bias — unused: softmax is invariant to per-row constants.
    float* out = (float*)d_out;                    // (B, 1, L)

    float* v = (float*)d_ws;        // B*H floats = 256 KB
    float* e = v + (size_t)B * H;   // B*L floats = 256 KB

    proj_hidden_kernel<<<B * (H / 256), 256, 0, stream>>>(hidden, W, v);
    energy_kernel<<<(B * L * 64) / 256, 256, 0, stream>>>(enc, v, e);
    softmax_kernel<<<B, 1024, 0, stream>>>(e, out);
}

// Round 3
// 360.612 us; speedup vs baseline: 1.1913x; 1.1913x over previous
//
#include <hip/hip_runtime.h>

#define H 1024
#define B 64
#define L 1024

typedef float vf4 __attribute__((ext_vector_type(4)));

// ---------------------------------------------------------------------------
// Kernel A: v[b,h] = sum_g hidden[b,g] * W[g,h]   (v = hidden @ W, 64x1024)
// Split-K version: grid = B * (H/64) = 1024 blocks, 256 threads (4 waves).
// Each block computes v[b, h0:h0+64]; wave `seg` accumulates g-range
// [seg*256, seg*256+256); LDS combine. 4x the blocks and 4x shorter
// dependence chains vs the 256-block version -> latency-hiding via TLP.
// W loads: 64 lanes contiguous (256 B/instr), L2-served after warmup (W=4MB).
// ---------------------------------------------------------------------------
__global__ __launch_bounds__(256) void proj_hidden_kernel(
    const float* __restrict__ hidden,
    const float* __restrict__ W,
    float* __restrict__ v) {
    __shared__ float sh[H];
    __shared__ float part[4][64];
    const int bid = blockIdx.x;
    const int b   = bid >> 4;          // / (H/64)
    const int h0  = (bid & 15) << 6;   // * 64
    const int tid = threadIdx.x;
    const int hl  = tid & 63;
    const int seg = tid >> 6;          // wave id = g-segment

    for (int i = tid; i < H; i += 256) sh[i] = hidden[b * H + i];
    __syncthreads();

    const int h = h0 + hl;
    const float* __restrict__ Wp = W + (size_t)(seg * 256) * H + h;
    const float* __restrict__ sp = sh + seg * 256;
    float acc = 0.f;
#pragma unroll 8
    for (int g = 0; g < 256; ++g) {
        acc += sp[g] * Wp[(size_t)g * H];   // sh read is wave-uniform broadcast
    }
    part[seg][hl] = acc;
    __syncthreads();
    if (tid < 64) {
        v[b * H + h0 + tid] =
            part[0][tid] + part[1][tid] + part[2][tid] + part[3][tid];
    }
}

// ---------------------------------------------------------------------------
// Kernel B: e[b,l] = dot(v[b,:], enc[l,b,:])
// One wave per (b, 4 consecutive l). v[b,:] loaded ONCE into 16 VGPRs and
// reused for 4 enc rows (L2 v-traffic /4, wave count /4 vs 1-l version).
// enc is a 268MB zero-reuse stream -> nontemporal loads keep it out of L2.
// Coalescing: wave reads a 4KB-contiguous enc row per j; the 4 waves of a
// block have consecutive b -> 16KB-contiguous span per j.
// ---------------------------------------------------------------------------
__global__ __launch_bounds__(256) void energy_kernel(
    const float* __restrict__ enc,
    const float* __restrict__ v,
    float* __restrict__ e) {
    const int wave = (blockIdx.x * 256 + threadIdx.x) >> 6;
    const int lane = threadIdx.x & 63;
    const int b  = wave & (B - 1);
    const int l0 = (wave >> 6) << 2;   // 4 l-values per wave

    const vf4* __restrict__ vp = reinterpret_cast<const vf4*>(v + (size_t)b * H);
    const vf4 w0 = vp[lane], w1 = vp[lane + 64], w2 = vp[lane + 128], w3 = vp[lane + 192];

    float acc[4];
#pragma unroll
    for (int j = 0; j < 4; ++j) {
        const vf4* __restrict__ ep =
            reinterpret_cast<const vf4*>(enc + ((size_t)(l0 + j) * B + b) * H);
        vf4 a0 = __builtin_nontemporal_load(ep + lane);
        vf4 a1 = __builtin_nontemporal_load(ep + lane + 64);
        vf4 a2 = __builtin_nontemporal_load(ep + lane + 128);
        vf4 a3 = __builtin_nontemporal_load(ep + lane + 192);
        acc[j] = a0.x * w0.x + a0.y * w0.y + a0.z * w0.z + a0.w * w0.w
               + a1.x * w1.x + a1.y * w1.y + a1.z * w1.z + a1.w * w1.w
               + a2.x * w2.x + a2.y * w2.y + a2.z * w2.z + a2.w * w2.w
               + a3.x * w3.x + a3.y * w3.y + a3.z * w3.z + a3.w * w3.w;
    }
#pragma unroll
    for (int off = 32; off; off >>= 1) {
#pragma unroll
        for (int j = 0; j < 4; ++j) acc[j] += __shfl_down(acc[j], off, 64);
    }
    if (lane == 0) {
#pragma unroll
        for (int j = 0; j < 4; ++j) e[(size_t)b * L + l0 + j] = acc[j];
    }
}

// ---------------------------------------------------------------------------
// Kernel C: row softmax over L=1024 per batch. 64 blocks x 1024 threads.
// (Bias term c[b] omitted: softmax is invariant to a per-row constant.)
// ---------------------------------------------------------------------------
__global__ __launch_bounds__(1024) void softmax_kernel(
    const float* __restrict__ e,
    float* __restrict__ out) {
    const int b = blockIdx.x;
    const int tid = threadIdx.x;
    const int wid = tid >> 6, lane = tid & 63;
    __shared__ float red[16];

    float x = e[(size_t)b * L + tid];

    float m = x;
#pragma unroll
    for (int off = 32; off; off >>= 1) m = fmaxf(m, __shfl_down(m, off, 64));
    if (lane == 0) red[wid] = m;
    __syncthreads();
    if (tid < 16) {
        float t = red[tid];
#pragma unroll
        for (int off = 8; off; off >>= 1) t = fmaxf(t, __shfl_down(t, off, 16));
        if (tid == 0) red[0] = t;
    }
    __syncthreads();
    m = red[0];
    __syncthreads();

    float ex = __expf(x - m);
    float s = ex;
#pragma unroll
    for (int off = 32; off; off >>= 1) s += __shfl_down(s, off, 64);
    if (lane == 0) red[wid] = s;
    __syncthreads();
    if (tid < 16) {
        float t = red[tid];
#pragma unroll
        for (int off = 8; off; off >>= 1) t += __shfl_down(t, off, 16);
        if (tid == 0) red[0] = t;
    }
    __syncthreads();
    s = red[0];

    out[(size_t)b * L + tid] = ex / s;
}

extern "C" void kernel_launch(void* const* d_in, const int* in_sizes, int n_in,
                              void* d_out, int out_size, void* d_ws, size_t ws_size,
                              hipStream_t stream) {
    const float* hidden = (const float*)d_in[0];   // (1, B, H)
    const float* enc    = (const float*)d_in[1];   // (L, B, H)
    const float* W      = (const float*)d_in[2];   // (H, H)
    // d_in[3] = bias — unused: softmax is invariant to per-row constants.
    float* out = (float*)d_out;                    // (B, 1, L)

    float* v = (float*)d_ws;        // B*H floats = 256 KB
    float* e = v + (size_t)B * H;   // B*L floats = 256 KB

    proj_hidden_kernel<<<B * (H / 64), 256, 0, stream>>>(hidden, W, v);
    energy_kernel<<<(B * L / 4) / 4, 256, 0, stream>>>(enc, v, e);
    softmax_kernel<<<B, 1024, 0, stream>>>(e, out);
}